// Round 7
// baseline (322.595 us; speedup 1.0000x reference)
//
#include <hip/hip_runtime.h>
#include <hip/hip_bf16.h>

typedef unsigned short u16;
typedef __attribute__((ext_vector_type(8))) short bf16x8;
typedef __attribute__((ext_vector_type(4))) float f32x4;

#define HEADS 4
#define OUT_DIM 64
#define HF 256          // HEADS*OUT_DIM
#define IN_DIM 128
#define NEG_SLOPE 0.2f
#define EPSF 1e-16f

__device__ __forceinline__ float braw2f(u16 u) {
    union { float f; unsigned int i; } c; c.i = ((unsigned int)u) << 16; return c.f;
}
__device__ __forceinline__ u16 f2braw(float v) {
    __hip_bfloat16 t = __float2bfloat16(v);
    return *(u16*)&t;
}
__device__ __forceinline__ float lrelu(float e) { return e < 0.f ? NEG_SLOPE * e : e; }

// edge_index contract says int32; defend against raw int64 (odd words all-zero).
__device__ __forceinline__ bool detect_i64(const int* ei) {
    return (ei[1] | ei[3] | ei[5] | ei[7] | ei[9] | ei[11] | ei[13] | ei[15]) == 0;
}
__device__ __forceinline__ void get_edge(const int* ei, int E, int t, bool i64,
                                         int& s, int& d) {
    if (t < E) {
        if (i64) { s = ei[2 * t]; d = ei[2 * (E + t)]; }
        else     { s = ei[t];     d = ei[E + t]; }
    } else {
        s = d = t - E;   // self loop
    }
}

// ---------- init: zero cnt (blocks 0..NZ-1) + fold wa = W*att (last block) ----
__global__ __launch_bounds__(256) void init_kernel(const float* __restrict__ W,
                                                   const float* __restrict__ att_s,
                                                   const float* __restrict__ att_d,
                                                   float* __restrict__ wa_s,
                                                   float* __restrict__ wa_d,
                                                   int* __restrict__ cnt, int N, int NZ) {
    int b = blockIdx.x;
    if (b < NZ) {
        int i = b * 256 + threadIdx.x;
        if (i < N) cnt[i] = 0;
    } else {
        for (int idx = threadIdx.x; idx < HEADS * IN_DIM; idx += 256) {
            int h = idx >> 7, k = idx & 127;
            float ss = 0.f, sd = 0.f;
            for (int f = 0; f < OUT_DIM; ++f) {
                float wv = W[k * HF + h * OUT_DIM + f];
                ss = fmaf(wv, att_s[h * OUT_DIM + f], ss);
                sd = fmaf(wv, att_d[h * OUT_DIM + f], sd);
            }
            wa_s[idx] = ss;
            wa_d[idx] = sd;
        }
    }
}

// ---------- phase1: [0,NA) logits + x->bf16 | [NA,NA+NC) count | tail Wfrag ----
__global__ __launch_bounds__(256) void phase1_kernel(const float* __restrict__ x,
                                                     const int* __restrict__ ei,
                                                     const float* __restrict__ W,
                                                     const float* __restrict__ wa_s,
                                                     const float* __restrict__ wa_d,
                                                     float* __restrict__ a_src,
                                                     float* __restrict__ a_dst,
                                                     u16* __restrict__ xb,
                                                     u16* __restrict__ Wfrag,
                                                     int* __restrict__ cnt,
                                                     int N, int E, int NA, int NC) {
    int b = blockIdx.x;
    if (b < NA) {
        // wave per node: logits + bf16 conversion (single pass over x)
        int v = (b * 256 + threadIdx.x) >> 6;
        int l = threadIdx.x & 63;
        if (v >= N) return;
        int h = l >> 4, c = l & 15, kc = c * 8;

        const float4* xr = (const float4*)(x + (size_t)v * IN_DIM + kc);
        float4 x0 = xr[0], x1 = xr[1];
        const float4* s4 = (const float4*)(wa_s + h * IN_DIM + kc);
        const float4* d4 = (const float4*)(wa_d + h * IN_DIM + kc);
        float4 s0 = s4[0], s1 = s4[1], d0 = d4[0], d1 = d4[1];

        float ps = x0.x*s0.x + x0.y*s0.y + x0.z*s0.z + x0.w*s0.w
                 + x1.x*s1.x + x1.y*s1.y + x1.z*s1.z + x1.w*s1.w;
        float pd = x0.x*d0.x + x0.y*d0.y + x0.z*d0.z + x0.w*d0.w
                 + x1.x*d1.x + x1.y*d1.y + x1.z*d1.z + x1.w*d1.w;
        #pragma unroll
        for (int off = 1; off < 16; off <<= 1) {
            ps += __shfl_xor(ps, off);
            pd += __shfl_xor(pd, off);
        }
        if (c == 0) {
            a_src[v * HEADS + h] = ps;
            a_dst[v * HEADS + h] = pd;
        }
        if (h == 0) {   // lanes 0..15 cover the whole row: write bf16 copy
            uint4 u;
            u.x = (unsigned)f2braw(x0.x) | ((unsigned)f2braw(x0.y) << 16);
            u.y = (unsigned)f2braw(x0.z) | ((unsigned)f2braw(x0.w) << 16);
            u.z = (unsigned)f2braw(x1.x) | ((unsigned)f2braw(x1.y) << 16);
            u.w = (unsigned)f2braw(x1.z) | ((unsigned)f2braw(x1.w) << 16);
            *(uint4*)(xb + (size_t)v * IN_DIM + kc) = u;
        }
    } else if (b < NA + NC) {
        int t = (b - NA) * 256 + threadIdx.x;
        if (t >= E + N) return;
        bool i64 = detect_i64(ei);
        int src, dst; get_edge(ei, E, t, i64, src, dst);
        if (src >= 0 && src < N && dst >= 0 && dst < N) atomicAdd(cnt + dst, 1);
    } else {
        int bb = b - NA - NC;   // 8 blocks
        for (int idx = bb * 256 + threadIdx.x; idx < 32768; idx += 8 * 256) {
            int j = idx & 7, l = (idx >> 3) & 63, t = (idx >> 9) & 3;
            int s = (idx >> 11) & 3, h = (idx >> 13) & 3;
            int k = s * 32 + ((l >> 4) & 3) * 8 + j;
            int col = h * OUT_DIM + t * 16 + (l & 15);
            Wfrag[idx] = f2braw(W[k * HF + col]);
        }
    }
}

// ---------- two-level scan ----------
__global__ __launch_bounds__(256) void scan1_kernel(const int* __restrict__ cnt,
                                                    int* __restrict__ indptr,
                                                    int* __restrict__ bsum, int N) {
    __shared__ int sc[256];
    int tid = threadIdx.x;
    int idx = blockIdx.x * 256 + tid;
    int v = (idx < N) ? cnt[idx] : 0;
    sc[tid] = v;
    __syncthreads();
    #pragma unroll
    for (int off = 1; off < 256; off <<= 1) {
        int t = (tid >= off) ? sc[tid - off] : 0;
        __syncthreads();
        sc[tid] += t;
        __syncthreads();
    }
    if (idx < N) indptr[idx + 1] = sc[tid];
    if (tid == 255) bsum[blockIdx.x] = sc[255];
}

__global__ __launch_bounds__(1024) void scan2_kernel(int* __restrict__ bsum, int T) {
    __shared__ int sc[1024];
    int tid = threadIdx.x;
    int v = (tid < T) ? bsum[tid] : 0;
    sc[tid] = v;
    __syncthreads();
    #pragma unroll
    for (int off = 1; off < 1024; off <<= 1) {
        int t = (tid >= off) ? sc[tid - off] : 0;
        __syncthreads();
        sc[tid] += t;
        __syncthreads();
    }
    if (tid < T) bsum[tid] = sc[tid] - v;   // exclusive
}

__global__ __launch_bounds__(256) void scan3_kernel(int* __restrict__ indptr,
                                                    const int* __restrict__ bsum,
                                                    int* __restrict__ cnt, int N) {
    int idx = blockIdx.x * 256 + threadIdx.x;
    if (idx < N) {
        indptr[idx + 1] += bsum[blockIdx.x];
        cnt[idx] = 0;
    }
    if (idx == 0) indptr[0] = 0;
}

__global__ __launch_bounds__(256) void fill_kernel(const int* __restrict__ ei,
                                                   const int* __restrict__ indptr,
                                                   int* __restrict__ cur,
                                                   int* __restrict__ slots, int E, int N) {
    int t = blockIdx.x * 256 + threadIdx.x;
    if (t >= E + N) return;
    bool i64 = detect_i64(ei);
    int src, dst; get_edge(ei, E, t, i64, src, dst);
    if (src >= 0 && src < N && dst >= 0 && dst < N) {
        int pos = atomicAdd(cur + dst, 1);
        slots[indptr[dst] + pos] = src;
    }
}

// ---------- gather: wave/node, 8 independent chains, bf16 x ----------
__global__ __launch_bounds__(512) void gather_bf_kernel(const int* __restrict__ indptr,
                                                        const int* __restrict__ slots,
                                                        const u16* __restrict__ xb,
                                                        const float* __restrict__ a_src,
                                                        const float* __restrict__ a_dst,
                                                        u16* __restrict__ Gout, int N, int ET) {
    int v = (blockIdx.x * 512 + threadIdx.x) >> 6;
    int l = threadIdx.x & 63;
    if (v >= N) return;
    int h = l >> 4, c = l & 15, kc = c * 8;

    int beg = indptr[v], end = indptr[v + 1];
    beg = max(0, min(beg, ET));
    end = max(beg, min(end, ET));
    float adh = a_dst[v * HEADS + h];

    float ls = 0.f;
    float G[8] = {0.f,0.f,0.f,0.f,0.f,0.f,0.f,0.f};

    int j = beg;
    for (; j + 8 <= end; j += 8) {
        int ss[8]; float w[8]; uint4 r[8];
        #pragma unroll
        for (int u = 0; u < 8; ++u) ss[u] = max(0, min(slots[j + u], N - 1));
        #pragma unroll
        for (int u = 0; u < 8; ++u)
            r[u] = *(const uint4*)(xb + (size_t)ss[u] * IN_DIM + kc);
        #pragma unroll
        for (int u = 0; u < 8; ++u)
            w[u] = __expf(lrelu(a_src[ss[u] * HEADS + h] + adh));
        #pragma unroll
        for (int u = 0; u < 8; ++u) {
            ls += w[u];
            G[0] = fmaf(w[u], braw2f(r[u].x & 0xffff), G[0]);
            G[1] = fmaf(w[u], braw2f(r[u].x >> 16),    G[1]);
            G[2] = fmaf(w[u], braw2f(r[u].y & 0xffff), G[2]);
            G[3] = fmaf(w[u], braw2f(r[u].y >> 16),    G[3]);
            G[4] = fmaf(w[u], braw2f(r[u].z & 0xffff), G[4]);
            G[5] = fmaf(w[u], braw2f(r[u].z >> 16),    G[5]);
            G[6] = fmaf(w[u], braw2f(r[u].w & 0xffff), G[6]);
            G[7] = fmaf(w[u], braw2f(r[u].w >> 16),    G[7]);
        }
    }
    for (; j < end; ++j) {
        int s0 = max(0, min(slots[j], N - 1));
        float w0 = __expf(lrelu(a_src[s0 * HEADS + h] + adh));
        uint4 r0 = *(const uint4*)(xb + (size_t)s0 * IN_DIM + kc);
        ls += w0;
        G[0] = fmaf(w0, braw2f(r0.x & 0xffff), G[0]);
        G[1] = fmaf(w0, braw2f(r0.x >> 16),    G[1]);
        G[2] = fmaf(w0, braw2f(r0.y & 0xffff), G[2]);
        G[3] = fmaf(w0, braw2f(r0.y >> 16),    G[3]);
        G[4] = fmaf(w0, braw2f(r0.z & 0xffff), G[4]);
        G[5] = fmaf(w0, braw2f(r0.z >> 16),    G[5]);
        G[6] = fmaf(w0, braw2f(r0.w & 0xffff), G[6]);
        G[7] = fmaf(w0, braw2f(r0.w >> 16),    G[7]);
    }

    float inv = 1.f / (ls + EPSF);
    uint4 u;
    u.x = (unsigned)f2braw(G[0] * inv) | ((unsigned)f2braw(G[1] * inv) << 16);
    u.y = (unsigned)f2braw(G[2] * inv) | ((unsigned)f2braw(G[3] * inv) << 16);
    u.z = (unsigned)f2braw(G[4] * inv) | ((unsigned)f2braw(G[5] * inv) << 16);
    u.w = (unsigned)f2braw(G[6] * inv) | ((unsigned)f2braw(G[7] * inv) << 16);
    *(uint4*)(Gout + (size_t)v * 512 + h * 128 + kc) = u;
}

// fp32-x fallback (if ws too small for xb)
__global__ __launch_bounds__(512) void gather_f32_kernel(const int* __restrict__ indptr,
                                                         const int* __restrict__ slots,
                                                         const float* __restrict__ x,
                                                         const float* __restrict__ a_src,
                                                         const float* __restrict__ a_dst,
                                                         u16* __restrict__ Gout, int N, int ET) {
    int v = (blockIdx.x * 512 + threadIdx.x) >> 6;
    int l = threadIdx.x & 63;
    if (v >= N) return;
    int h = l >> 4, c = l & 15, kc = c * 8;

    int beg = indptr[v], end = indptr[v + 1];
    beg = max(0, min(beg, ET));
    end = max(beg, min(end, ET));
    float adh = a_dst[v * HEADS + h];

    float ls = 0.f;
    float G[8] = {0.f,0.f,0.f,0.f,0.f,0.f,0.f,0.f};
    for (int j = beg; j < end; ++j) {
        int s0 = max(0, min(slots[j], N - 1));
        float w0 = __expf(lrelu(a_src[s0 * HEADS + h] + adh));
        const float4* xr0 = (const float4*)(x + (size_t)s0 * IN_DIM + kc);
        float4 a0 = xr0[0], b0 = xr0[1];
        ls += w0;
        G[0]=fmaf(w0,a0.x,G[0]); G[1]=fmaf(w0,a0.y,G[1]);
        G[2]=fmaf(w0,a0.z,G[2]); G[3]=fmaf(w0,a0.w,G[3]);
        G[4]=fmaf(w0,b0.x,G[4]); G[5]=fmaf(w0,b0.y,G[5]);
        G[6]=fmaf(w0,b0.z,G[6]); G[7]=fmaf(w0,b0.w,G[7]);
    }
    float inv = 1.f / (ls + EPSF);
    uint4 u;
    u.x = (unsigned)f2braw(G[0] * inv) | ((unsigned)f2braw(G[1] * inv) << 16);
    u.y = (unsigned)f2braw(G[2] * inv) | ((unsigned)f2braw(G[3] * inv) << 16);
    u.z = (unsigned)f2braw(G[4] * inv) | ((unsigned)f2braw(G[5] * inv) << 16);
    u.w = (unsigned)f2braw(G[6] * inv) | ((unsigned)f2braw(G[7] * inv) << 16);
    *(uint4*)(Gout + (size_t)v * 512 + h * 128 + kc) = u;
}

// ---------- zgemm: z_h = G_h @ W_h via MFMA; fused bias+mix; in-place over G ---
__global__ __launch_bounds__(256) void zgemm_kernel(const u16* __restrict__ Wfrag,
                                                    const float* __restrict__ bias,
                                                    float* __restrict__ out, int N) {
    int h = threadIdx.x >> 6;
    int l = threadIdx.x & 63;
    int q = l >> 4, mcol = l & 15;
    int nb = blockIdx.x * 16;

    const u16* G = (const u16*)out;
    bool valid = (nb + mcol) < N;
    int vA = valid ? nb + mcol : N - 1;
    const u16* gp = G + (size_t)vA * 512 + h * 128 + q * 8;
    bf16x8 A[4];
    A[0] = *(const bf16x8*)(gp);
    A[1] = *(const bf16x8*)(gp + 32);
    A[2] = *(const bf16x8*)(gp + 64);
    A[3] = *(const bf16x8*)(gp + 96);
    if (!valid) {
        bf16x8 zz = {0,0,0,0,0,0,0,0};
        A[0] = zz; A[1] = zz; A[2] = zz; A[3] = zz;
    }

    f32x4 acc0 = {0.f,0.f,0.f,0.f}, acc1 = acc0, acc2 = acc0, acc3 = acc0;
    #pragma unroll
    for (int s = 0; s < 4; ++s) {
        const u16* wb = Wfrag + (((h * 4 + s) * 4) << 9) + l * 8;
        bf16x8 B0 = *(const bf16x8*)(wb);
        bf16x8 B1 = *(const bf16x8*)(wb + 512);
        bf16x8 B2 = *(const bf16x8*)(wb + 1024);
        bf16x8 B3 = *(const bf16x8*)(wb + 1536);
        acc0 = __builtin_amdgcn_mfma_f32_16x16x32_bf16(A[s], B0, acc0, 0, 0, 0);
        acc1 = __builtin_amdgcn_mfma_f32_16x16x32_bf16(A[s], B1, acc1, 0, 0, 0);
        acc2 = __builtin_amdgcn_mfma_f32_16x16x32_bf16(A[s], B2, acc2, 0, 0, 0);
        acc3 = __builtin_amdgcn_mfma_f32_16x16x32_bf16(A[s], B3, acc3, 0, 0, 0);
    }

    #pragma unroll
    for (int t = 0; t < 4; ++t) {
        f32x4 a = t == 0 ? acc0 : t == 1 ? acc1 : t == 2 ? acc2 : acc3;
        float b = bias[h * OUT_DIM + t * 16 + mcol];
        #pragma unroll
        for (int r = 0; r < 4; ++r) {
            int v = nb + q * 4 + r;
            if (v < N) {
                float z = a[r] + b;
                float y = z > 0.f ? z : 0.5f * z + 0.5f * (__expf(z) - 1.f);
                out[(size_t)v * HF + h * OUT_DIM + t * 16 + mcol] = y;
            }
        }
    }
}

extern "C" void kernel_launch(void* const* d_in, const int* in_sizes, int n_in,
                              void* d_out, int out_size, void* d_ws, size_t ws_size,
                              hipStream_t stream) {
    const float* x       = (const float*)d_in[0];
    const int*   ei      = (const int*)d_in[1];
    const float* W       = (const float*)d_in[2];
    const float* att_src = (const float*)d_in[3];
    const float* att_dst = (const float*)d_in[4];
    const float* bias    = (const float*)d_in[5];

    const int N = in_sizes[0] / IN_DIM;   // 50000
    const int E = in_sizes[1] / 2;        // 800000
    const int ET = E + N;
    const int NT = (N + 255) / 256;       // 196 scan tiles

    // ws layout: wa_s | wa_d | Wfrag | a_src | a_dst | indptr | cnt | bsum | slots | [xb]
    char* ws = (char*)d_ws;
    size_t off = 0;
    float* wa_s   = (float*)(ws + off); off += HEADS * IN_DIM * 4;
    float* wa_d   = (float*)(ws + off); off += HEADS * IN_DIM * 4;
    u16*   Wfrag  = (u16*)(ws + off);   off += 32768 * 2;
    float* a_src  = (float*)(ws + off); off += (size_t)N * HEADS * 4;
    float* a_dst  = (float*)(ws + off); off += (size_t)N * HEADS * 4;
    int*   indptr = (int*)(ws + off);   off += ((size_t)(N + 1) * 4 + 15) & ~(size_t)15;
    int*   cnt    = (int*)(ws + off);   off += ((size_t)N * 4 + 15) & ~(size_t)15;
    int*   bsum   = (int*)(ws + off);   off += 1024 * 4;
    int*   slots  = (int*)(ws + off);   off += ((size_t)ET * 4 + 15) & ~(size_t)15;
    u16*   xb     = (u16*)(ws + off);
    size_t need_bf = off + (size_t)N * IN_DIM * 2;
    bool use_bf = (ws_size >= need_bf);

    const int NA = (N + 3) / 4;           // a+xcvt blocks (wave per node, 256 thr)
    const int NC = (ET + 255) / 256;      // count blocks

    init_kernel<<<NT + 1, 256, 0, stream>>>(W, att_src, att_dst, wa_s, wa_d, cnt, N, NT);
    phase1_kernel<<<NA + NC + 8, 256, 0, stream>>>(x, ei, W, wa_s, wa_d, a_src, a_dst,
                                                   use_bf ? xb : (u16*)d_out,  // xb always writable
                                                   Wfrag, cnt, N, E, NA, NC);
    scan1_kernel<<<NT, 256, 0, stream>>>(cnt, indptr, bsum, N);
    scan2_kernel<<<1, 1024, 0, stream>>>(bsum, NT);
    scan3_kernel<<<NT, 256, 0, stream>>>(indptr, bsum, cnt, N);
    fill_kernel<<<(ET + 255) / 256, 256, 0, stream>>>(ei, indptr, cnt, slots, E, N);
    if (use_bf) {
        gather_bf_kernel<<<(N * 64 + 511) / 512, 512, 0, stream>>>(indptr, slots, xb,
                                                                   a_src, a_dst,
                                                                   (u16*)d_out, N, ET);
    } else {
        gather_f32_kernel<<<(N * 64 + 511) / 512, 512, 0, stream>>>(indptr, slots, x,
                                                                    a_src, a_dst,
                                                                    (u16*)d_out, N, ET);
    }
    zgemm_kernel<<<(N + 15) / 16, 256, 0, stream>>>(Wfrag, bias, (float*)d_out, N);
}

// Round 8
// 267.561 us; speedup vs baseline: 1.2057x; 1.2057x over previous
//
#include <hip/hip_runtime.h>
#include <hip/hip_bf16.h>

typedef unsigned short u16;
typedef __attribute__((ext_vector_type(8))) short bf16x8;
typedef __attribute__((ext_vector_type(4))) float f32x4;

#define HEADS 4
#define OUT_DIM 64
#define HF 256          // HEADS*OUT_DIM
#define IN_DIM 128
#define NEG_SLOPE 0.2f
#define EPSF 1e-16f

__device__ __forceinline__ float braw2f(u16 u) {
    union { float f; unsigned int i; } c; c.i = ((unsigned int)u) << 16; return c.f;
}
__device__ __forceinline__ u16 f2braw(float v) {
    __hip_bfloat16 t = __float2bfloat16(v);
    return *(u16*)&t;
}
__device__ __forceinline__ float lrelu(float e) { return e < 0.f ? NEG_SLOPE * e : e; }

// edge_index contract says int32; defend against raw int64 (odd words all-zero).
__device__ __forceinline__ bool detect_i64(const int* ei) {
    return (ei[1] | ei[3] | ei[5] | ei[7] | ei[9] | ei[11] | ei[13] | ei[15]) == 0;
}
__device__ __forceinline__ void get_edge(const int* ei, int E, int t, bool i64,
                                         int& s, int& d) {
    if (t < E) {
        if (i64) { s = ei[2 * t]; d = ei[2 * (E + t)]; }
        else     { s = ei[t];     d = ei[E + t]; }
    } else {
        s = d = t - E;   // self loop
    }
}

// ---------- init: zero cnt (blocks 0..NZ-1) + fold wa = W*att (last block) ----
__global__ __launch_bounds__(256) void init_kernel(const float* __restrict__ W,
                                                   const float* __restrict__ att_s,
                                                   const float* __restrict__ att_d,
                                                   float* __restrict__ wa_s,
                                                   float* __restrict__ wa_d,
                                                   int* __restrict__ cnt, int N, int NZ) {
    int b = blockIdx.x;
    if (b < NZ) {
        int i = b * 256 + threadIdx.x;
        if (i < N) cnt[i] = 0;
    } else {
        for (int idx = threadIdx.x; idx < HEADS * IN_DIM; idx += 256) {
            int h = idx >> 7, k = idx & 127;
            float ss = 0.f, sd = 0.f;
            for (int f = 0; f < OUT_DIM; ++f) {
                float wv = W[k * HF + h * OUT_DIM + f];
                ss = fmaf(wv, att_s[h * OUT_DIM + f], ss);
                sd = fmaf(wv, att_d[h * OUT_DIM + f], sd);
            }
            wa_s[idx] = ss;
            wa_d[idx] = sd;
        }
    }
}

// ---------- phase1: [0,NA) logits + x->bf16 | [NA,NA+NC) count | tail Wfrag ----
__global__ __launch_bounds__(256) void phase1_kernel(const float* __restrict__ x,
                                                     const int* __restrict__ ei,
                                                     const float* __restrict__ W,
                                                     const float* __restrict__ wa_s,
                                                     const float* __restrict__ wa_d,
                                                     float* __restrict__ a_src,
                                                     float* __restrict__ a_dst,
                                                     u16* __restrict__ xb,
                                                     u16* __restrict__ Wfrag,
                                                     int* __restrict__ cnt,
                                                     int N, int E, int NA, int NC) {
    int b = blockIdx.x;
    if (b < NA) {
        int v = (b * 256 + threadIdx.x) >> 6;
        int l = threadIdx.x & 63;
        if (v >= N) return;
        int h = l >> 4, c = l & 15, kc = c * 8;

        const float4* xr = (const float4*)(x + (size_t)v * IN_DIM + kc);
        float4 x0 = xr[0], x1 = xr[1];
        const float4* s4 = (const float4*)(wa_s + h * IN_DIM + kc);
        const float4* d4 = (const float4*)(wa_d + h * IN_DIM + kc);
        float4 s0 = s4[0], s1 = s4[1], d0 = d4[0], d1 = d4[1];

        float ps = x0.x*s0.x + x0.y*s0.y + x0.z*s0.z + x0.w*s0.w
                 + x1.x*s1.x + x1.y*s1.y + x1.z*s1.z + x1.w*s1.w;
        float pd = x0.x*d0.x + x0.y*d0.y + x0.z*d0.z + x0.w*d0.w
                 + x1.x*d1.x + x1.y*d1.y + x1.z*d1.z + x1.w*d1.w;
        #pragma unroll
        for (int off = 1; off < 16; off <<= 1) {
            ps += __shfl_xor(ps, off);
            pd += __shfl_xor(pd, off);
        }
        if (c == 0) {
            a_src[v * HEADS + h] = ps;
            a_dst[v * HEADS + h] = pd;
        }
        if (h == 0) {   // lanes 0..15 cover the whole row: write bf16 copy
            uint4 u;
            u.x = (unsigned)f2braw(x0.x) | ((unsigned)f2braw(x0.y) << 16);
            u.y = (unsigned)f2braw(x0.z) | ((unsigned)f2braw(x0.w) << 16);
            u.z = (unsigned)f2braw(x1.x) | ((unsigned)f2braw(x1.y) << 16);
            u.w = (unsigned)f2braw(x1.z) | ((unsigned)f2braw(x1.w) << 16);
            *(uint4*)(xb + (size_t)v * IN_DIM + kc) = u;
        }
    } else if (b < NA + NC) {
        int t = (b - NA) * 256 + threadIdx.x;
        if (t >= E + N) return;
        bool i64 = detect_i64(ei);
        int src, dst; get_edge(ei, E, t, i64, src, dst);
        if (src >= 0 && src < N && dst >= 0 && dst < N) atomicAdd(cnt + dst, 1);
    } else {
        int bb = b - NA - NC;   // 8 blocks
        for (int idx = bb * 256 + threadIdx.x; idx < 32768; idx += 8 * 256) {
            int j = idx & 7, l = (idx >> 3) & 63, t = (idx >> 9) & 3;
            int s = (idx >> 11) & 3, h = (idx >> 13) & 3;
            int k = s * 32 + ((l >> 4) & 3) * 8 + j;
            int col = h * OUT_DIM + t * 16 + (l & 15);
            Wfrag[idx] = f2braw(W[k * HF + col]);
        }
    }
}

// ---------- two-level scan ----------
__global__ __launch_bounds__(256) void scan1_kernel(const int* __restrict__ cnt,
                                                    int* __restrict__ indptr,
                                                    int* __restrict__ bsum, int N) {
    __shared__ int sc[256];
    int tid = threadIdx.x;
    int idx = blockIdx.x * 256 + tid;
    int v = (idx < N) ? cnt[idx] : 0;
    sc[tid] = v;
    __syncthreads();
    #pragma unroll
    for (int off = 1; off < 256; off <<= 1) {
        int t = (tid >= off) ? sc[tid - off] : 0;
        __syncthreads();
        sc[tid] += t;
        __syncthreads();
    }
    if (idx < N) indptr[idx + 1] = sc[tid];
    if (tid == 255) bsum[blockIdx.x] = sc[255];
}

__global__ __launch_bounds__(1024) void scan2_kernel(int* __restrict__ bsum, int T) {
    __shared__ int sc[1024];
    int tid = threadIdx.x;
    int v = (tid < T) ? bsum[tid] : 0;
    sc[tid] = v;
    __syncthreads();
    #pragma unroll
    for (int off = 1; off < 1024; off <<= 1) {
        int t = (tid >= off) ? sc[tid - off] : 0;
        __syncthreads();
        sc[tid] += t;
        __syncthreads();
    }
    if (tid < T) bsum[tid] = sc[tid] - v;   // exclusive
}

__global__ __launch_bounds__(256) void scan3_kernel(int* __restrict__ indptr,
                                                    const int* __restrict__ bsum,
                                                    int* __restrict__ cnt, int N) {
    int idx = blockIdx.x * 256 + threadIdx.x;
    if (idx < N) {
        indptr[idx + 1] += bsum[blockIdx.x];
        cnt[idx] = 0;
    }
    if (idx == 0) indptr[0] = 0;
}

// ---------- fill: build slots + per-edge packed bf16 exp-weights ----------
__global__ __launch_bounds__(256) void fill_kernel(const int* __restrict__ ei,
                                                   const int* __restrict__ indptr,
                                                   int* __restrict__ cur,
                                                   int* __restrict__ slots,
                                                   uint2* __restrict__ wslots,
                                                   const float* __restrict__ a_src,
                                                   const float* __restrict__ a_dst,
                                                   int E, int N) {
    int t = blockIdx.x * 256 + threadIdx.x;
    if (t >= E + N) return;
    bool i64 = detect_i64(ei);
    int src, dst; get_edge(ei, E, t, i64, src, dst);
    if (src >= 0 && src < N && dst >= 0 && dst < N) {
        int pos = atomicAdd(cur + dst, 1);
        int idx = indptr[dst] + pos;
        slots[idx] = src;
        if (wslots) {
            float4 as = ((const float4*)a_src)[src];
            float4 ad = ((const float4*)a_dst)[dst];
            float w0 = __expf(lrelu(as.x + ad.x));
            float w1 = __expf(lrelu(as.y + ad.y));
            float w2 = __expf(lrelu(as.z + ad.z));
            float w3 = __expf(lrelu(as.w + ad.w));
            uint2 wp;
            wp.x = (unsigned)f2braw(w0) | ((unsigned)f2braw(w1) << 16);
            wp.y = (unsigned)f2braw(w2) | ((unsigned)f2braw(w3) << 16);
            wslots[idx] = wp;
        }
    }
}

// ---------- gather_w: 16 lanes/node (4 nodes/wave), precomputed weights -------
// Lane c of node-group holds dims kc..kc+7 for ALL 4 heads (G[4][8], 32 VGPR).
// Row read is non-redundant (16 lanes x 16B = 256B row). 2-deep manual pipeline.
__global__ __launch_bounds__(512) void gather_w_kernel(const int* __restrict__ indptr,
                                                       const int* __restrict__ slots,
                                                       const uint2* __restrict__ wslots,
                                                       const u16* __restrict__ xb,
                                                       u16* __restrict__ Gout, int N, int ET) {
    int l = threadIdx.x & 63;
    int gw = blockIdx.x * 8 + (threadIdx.x >> 6);
    int v = gw * 4 + (l >> 4);
    if (v >= N) return;
    int c = l & 15, kc = c * 8;

    int beg = indptr[v], end = indptr[v + 1];
    beg = max(0, min(beg, ET));
    end = max(beg, min(end, ET));

    float ls0 = 0.f, ls1 = 0.f, ls2 = 0.f, ls3 = 0.f;
    float G0[8] = {0,0,0,0,0,0,0,0};
    float G1[8] = {0,0,0,0,0,0,0,0};
    float G2[8] = {0,0,0,0,0,0,0,0};
    float G3[8] = {0,0,0,0,0,0,0,0};

    int j = beg;
    for (; j + 2 <= end; j += 2) {
        int s0 = max(0, min(slots[j],     N - 1));
        int s1 = max(0, min(slots[j + 1], N - 1));
        uint2 wp0 = wslots[j];
        uint2 wp1 = wslots[j + 1];
        uint4 r0 = *(const uint4*)(xb + (size_t)s0 * IN_DIM + kc);
        uint4 r1 = *(const uint4*)(xb + (size_t)s1 * IN_DIM + kc);

        float a0 = braw2f(wp0.x & 0xffff), a1 = braw2f(wp0.x >> 16);
        float a2 = braw2f(wp0.y & 0xffff), a3 = braw2f(wp0.y >> 16);
        ls0 += a0; ls1 += a1; ls2 += a2; ls3 += a3;
        {
            float xv[8];
            xv[0] = braw2f(r0.x & 0xffff); xv[1] = braw2f(r0.x >> 16);
            xv[2] = braw2f(r0.y & 0xffff); xv[3] = braw2f(r0.y >> 16);
            xv[4] = braw2f(r0.z & 0xffff); xv[5] = braw2f(r0.z >> 16);
            xv[6] = braw2f(r0.w & 0xffff); xv[7] = braw2f(r0.w >> 16);
            #pragma unroll
            for (int q = 0; q < 8; ++q) {
                G0[q] = fmaf(a0, xv[q], G0[q]);
                G1[q] = fmaf(a1, xv[q], G1[q]);
                G2[q] = fmaf(a2, xv[q], G2[q]);
                G3[q] = fmaf(a3, xv[q], G3[q]);
            }
        }
        float b0 = braw2f(wp1.x & 0xffff), b1 = braw2f(wp1.x >> 16);
        float b2 = braw2f(wp1.y & 0xffff), b3 = braw2f(wp1.y >> 16);
        ls0 += b0; ls1 += b1; ls2 += b2; ls3 += b3;
        {
            float xv[8];
            xv[0] = braw2f(r1.x & 0xffff); xv[1] = braw2f(r1.x >> 16);
            xv[2] = braw2f(r1.y & 0xffff); xv[3] = braw2f(r1.y >> 16);
            xv[4] = braw2f(r1.z & 0xffff); xv[5] = braw2f(r1.z >> 16);
            xv[6] = braw2f(r1.w & 0xffff); xv[7] = braw2f(r1.w >> 16);
            #pragma unroll
            for (int q = 0; q < 8; ++q) {
                G0[q] = fmaf(b0, xv[q], G0[q]);
                G1[q] = fmaf(b1, xv[q], G1[q]);
                G2[q] = fmaf(b2, xv[q], G2[q]);
                G3[q] = fmaf(b3, xv[q], G3[q]);
            }
        }
    }
    if (j < end) {
        int s0 = max(0, min(slots[j], N - 1));
        uint2 wp0 = wslots[j];
        uint4 r0 = *(const uint4*)(xb + (size_t)s0 * IN_DIM + kc);
        float a0 = braw2f(wp0.x & 0xffff), a1 = braw2f(wp0.x >> 16);
        float a2 = braw2f(wp0.y & 0xffff), a3 = braw2f(wp0.y >> 16);
        ls0 += a0; ls1 += a1; ls2 += a2; ls3 += a3;
        float xv[8];
        xv[0] = braw2f(r0.x & 0xffff); xv[1] = braw2f(r0.x >> 16);
        xv[2] = braw2f(r0.y & 0xffff); xv[3] = braw2f(r0.y >> 16);
        xv[4] = braw2f(r0.z & 0xffff); xv[5] = braw2f(r0.z >> 16);
        xv[6] = braw2f(r0.w & 0xffff); xv[7] = braw2f(r0.w >> 16);
        #pragma unroll
        for (int q = 0; q < 8; ++q) {
            G0[q] = fmaf(a0, xv[q], G0[q]);
            G1[q] = fmaf(a1, xv[q], G1[q]);
            G2[q] = fmaf(a2, xv[q], G2[q]);
            G3[q] = fmaf(a3, xv[q], G3[q]);
        }
    }

    float i0 = 1.f / (ls0 + EPSF), i1 = 1.f / (ls1 + EPSF);
    float i2 = 1.f / (ls2 + EPSF), i3 = 1.f / (ls3 + EPSF);
    u16* gout = Gout + (size_t)v * 512 + kc;
    #pragma unroll
    for (int h = 0; h < 4; ++h) {
        const float* G = h == 0 ? G0 : h == 1 ? G1 : h == 2 ? G2 : G3;
        float inv = h == 0 ? i0 : h == 1 ? i1 : h == 2 ? i2 : i3;
        uint4 u;
        u.x = (unsigned)f2braw(G[0] * inv) | ((unsigned)f2braw(G[1] * inv) << 16);
        u.y = (unsigned)f2braw(G[2] * inv) | ((unsigned)f2braw(G[3] * inv) << 16);
        u.z = (unsigned)f2braw(G[4] * inv) | ((unsigned)f2braw(G[5] * inv) << 16);
        u.w = (unsigned)f2braw(G[6] * inv) | ((unsigned)f2braw(G[7] * inv) << 16);
        *(uint4*)(gout + h * 128) = u;
    }
}

// ---------- fallback gather (R6-proven, 4-way, inline exp) ----------
__global__ __launch_bounds__(512) void gather_bf_kernel(const int* __restrict__ indptr,
                                                        const int* __restrict__ slots,
                                                        const u16* __restrict__ xb,
                                                        const float* __restrict__ a_src,
                                                        const float* __restrict__ a_dst,
                                                        u16* __restrict__ Gout, int N, int ET) {
    int v = (blockIdx.x * 512 + threadIdx.x) >> 6;
    int l = threadIdx.x & 63;
    if (v >= N) return;
    int h = l >> 4, c = l & 15, kc = c * 8;

    int beg = indptr[v], end = indptr[v + 1];
    beg = max(0, min(beg, ET));
    end = max(beg, min(end, ET));
    float adh = a_dst[v * HEADS + h];

    float ls = 0.f;
    float G[8] = {0.f,0.f,0.f,0.f,0.f,0.f,0.f,0.f};

    int j = beg;
    for (; j + 4 <= end; j += 4) {
        int s0 = max(0, min(slots[j],     N - 1));
        int s1 = max(0, min(slots[j + 1], N - 1));
        int s2 = max(0, min(slots[j + 2], N - 1));
        int s3 = max(0, min(slots[j + 3], N - 1));
        float w0 = __expf(lrelu(a_src[s0 * HEADS + h] + adh));
        float w1 = __expf(lrelu(a_src[s1 * HEADS + h] + adh));
        float w2 = __expf(lrelu(a_src[s2 * HEADS + h] + adh));
        float w3 = __expf(lrelu(a_src[s3 * HEADS + h] + adh));
        uint4 r0 = *(const uint4*)(xb + (size_t)s0 * IN_DIM + kc);
        uint4 r1 = *(const uint4*)(xb + (size_t)s1 * IN_DIM + kc);
        uint4 r2 = *(const uint4*)(xb + (size_t)s2 * IN_DIM + kc);
        uint4 r3 = *(const uint4*)(xb + (size_t)s3 * IN_DIM + kc);
        ls += (w0 + w1) + (w2 + w3);
        unsigned ua[4];
        ua[0]=r0.x; ua[1]=r0.y; ua[2]=r0.z; ua[3]=r0.w;
        #pragma unroll
        for (int q = 0; q < 4; ++q) {
            G[2*q]   = fmaf(w0, braw2f(ua[q] & 0xffff), G[2*q]);
            G[2*q+1] = fmaf(w0, braw2f(ua[q] >> 16),    G[2*q+1]);
        }
        ua[0]=r1.x; ua[1]=r1.y; ua[2]=r1.z; ua[3]=r1.w;
        #pragma unroll
        for (int q = 0; q < 4; ++q) {
            G[2*q]   = fmaf(w1, braw2f(ua[q] & 0xffff), G[2*q]);
            G[2*q+1] = fmaf(w1, braw2f(ua[q] >> 16),    G[2*q+1]);
        }
        ua[0]=r2.x; ua[1]=r2.y; ua[2]=r2.z; ua[3]=r2.w;
        #pragma unroll
        for (int q = 0; q < 4; ++q) {
            G[2*q]   = fmaf(w2, braw2f(ua[q] & 0xffff), G[2*q]);
            G[2*q+1] = fmaf(w2, braw2f(ua[q] >> 16),    G[2*q+1]);
        }
        ua[0]=r3.x; ua[1]=r3.y; ua[2]=r3.z; ua[3]=r3.w;
        #pragma unroll
        for (int q = 0; q < 4; ++q) {
            G[2*q]   = fmaf(w3, braw2f(ua[q] & 0xffff), G[2*q]);
            G[2*q+1] = fmaf(w3, braw2f(ua[q] >> 16),    G[2*q+1]);
        }
    }
    for (; j < end; ++j) {
        int s0 = max(0, min(slots[j], N - 1));
        float w0 = __expf(lrelu(a_src[s0 * HEADS + h] + adh));
        uint4 r0 = *(const uint4*)(xb + (size_t)s0 * IN_DIM + kc);
        ls += w0;
        unsigned ua[4]; ua[0]=r0.x; ua[1]=r0.y; ua[2]=r0.z; ua[3]=r0.w;
        #pragma unroll
        for (int q = 0; q < 4; ++q) {
            G[2*q]   = fmaf(w0, braw2f(ua[q] & 0xffff), G[2*q]);
            G[2*q+1] = fmaf(w0, braw2f(ua[q] >> 16),    G[2*q+1]);
        }
    }

    float inv = 1.f / (ls + EPSF);
    uint4 u;
    u.x = (unsigned)f2braw(G[0] * inv) | ((unsigned)f2braw(G[1] * inv) << 16);
    u.y = (unsigned)f2braw(G[2] * inv) | ((unsigned)f2braw(G[3] * inv) << 16);
    u.z = (unsigned)f2braw(G[4] * inv) | ((unsigned)f2braw(G[5] * inv) << 16);
    u.w = (unsigned)f2braw(G[6] * inv) | ((unsigned)f2braw(G[7] * inv) << 16);
    *(uint4*)(Gout + (size_t)v * 512 + h * 128 + kc) = u;
}

// fp32-x fallback (if ws too small for xb)
__global__ __launch_bounds__(512) void gather_f32_kernel(const int* __restrict__ indptr,
                                                         const int* __restrict__ slots,
                                                         const float* __restrict__ x,
                                                         const float* __restrict__ a_src,
                                                         const float* __restrict__ a_dst,
                                                         u16* __restrict__ Gout, int N, int ET) {
    int v = (blockIdx.x * 512 + threadIdx.x) >> 6;
    int l = threadIdx.x & 63;
    if (v >= N) return;
    int h = l >> 4, c = l & 15, kc = c * 8;

    int beg = indptr[v], end = indptr[v + 1];
    beg = max(0, min(beg, ET));
    end = max(beg, min(end, ET));
    float adh = a_dst[v * HEADS + h];

    float ls = 0.f;
    float G[8] = {0.f,0.f,0.f,0.f,0.f,0.f,0.f,0.f};
    for (int j = beg; j < end; ++j) {
        int s0 = max(0, min(slots[j], N - 1));
        float w0 = __expf(lrelu(a_src[s0 * HEADS + h] + adh));
        const float4* xr0 = (const float4*)(x + (size_t)s0 * IN_DIM + kc);
        float4 a0 = xr0[0], b0 = xr0[1];
        ls += w0;
        G[0]=fmaf(w0,a0.x,G[0]); G[1]=fmaf(w0,a0.y,G[1]);
        G[2]=fmaf(w0,a0.z,G[2]); G[3]=fmaf(w0,a0.w,G[3]);
        G[4]=fmaf(w0,b0.x,G[4]); G[5]=fmaf(w0,b0.y,G[5]);
        G[6]=fmaf(w0,b0.z,G[6]); G[7]=fmaf(w0,b0.w,G[7]);
    }
    float inv = 1.f / (ls + EPSF);
    uint4 u;
    u.x = (unsigned)f2braw(G[0] * inv) | ((unsigned)f2braw(G[1] * inv) << 16);
    u.y = (unsigned)f2braw(G[2] * inv) | ((unsigned)f2braw(G[3] * inv) << 16);
    u.z = (unsigned)f2braw(G[4] * inv) | ((unsigned)f2braw(G[5] * inv) << 16);
    u.w = (unsigned)f2braw(G[6] * inv) | ((unsigned)f2braw(G[7] * inv) << 16);
    *(uint4*)(Gout + (size_t)v * 512 + h * 128 + kc) = u;
}

// ---------- zgemm: z_h = G_h @ W_h via MFMA; fused bias+mix; in-place over G ---
__global__ __launch_bounds__(256) void zgemm_kernel(const u16* __restrict__ Wfrag,
                                                    const float* __restrict__ bias,
                                                    float* __restrict__ out, int N) {
    int h = threadIdx.x >> 6;
    int l = threadIdx.x & 63;
    int q = l >> 4, mcol = l & 15;
    int nb = blockIdx.x * 16;

    const u16* G = (const u16*)out;
    bool valid = (nb + mcol) < N;
    int vA = valid ? nb + mcol : N - 1;
    const u16* gp = G + (size_t)vA * 512 + h * 128 + q * 8;
    bf16x8 A[4];
    A[0] = *(const bf16x8*)(gp);
    A[1] = *(const bf16x8*)(gp + 32);
    A[2] = *(const bf16x8*)(gp + 64);
    A[3] = *(const bf16x8*)(gp + 96);
    if (!valid) {
        bf16x8 zz = {0,0,0,0,0,0,0,0};
        A[0] = zz; A[1] = zz; A[2] = zz; A[3] = zz;
    }

    f32x4 acc0 = {0.f,0.f,0.f,0.f}, acc1 = acc0, acc2 = acc0, acc3 = acc0;
    #pragma unroll
    for (int s = 0; s < 4; ++s) {
        const u16* wb = Wfrag + (((h * 4 + s) * 4) << 9) + l * 8;
        bf16x8 B0 = *(const bf16x8*)(wb);
        bf16x8 B1 = *(const bf16x8*)(wb + 512);
        bf16x8 B2 = *(const bf16x8*)(wb + 1024);
        bf16x8 B3 = *(const bf16x8*)(wb + 1536);
        acc0 = __builtin_amdgcn_mfma_f32_16x16x32_bf16(A[s], B0, acc0, 0, 0, 0);
        acc1 = __builtin_amdgcn_mfma_f32_16x16x32_bf16(A[s], B1, acc1, 0, 0, 0);
        acc2 = __builtin_amdgcn_mfma_f32_16x16x32_bf16(A[s], B2, acc2, 0, 0, 0);
        acc3 = __builtin_amdgcn_mfma_f32_16x16x32_bf16(A[s], B3, acc3, 0, 0, 0);
    }

    #pragma unroll
    for (int t = 0; t < 4; ++t) {
        f32x4 a = t == 0 ? acc0 : t == 1 ? acc1 : t == 2 ? acc2 : acc3;
        float b = bias[h * OUT_DIM + t * 16 + mcol];
        #pragma unroll
        for (int r = 0; r < 4; ++r) {
            int v = nb + q * 4 + r;
            if (v < N) {
                float z = a[r] + b;
                float y = z > 0.f ? z : 0.5f * z + 0.5f * (__expf(z) - 1.f);
                out[(size_t)v * HF + h * OUT_DIM + t * 16 + mcol] = y;
            }
        }
    }
}

extern "C" void kernel_launch(void* const* d_in, const int* in_sizes, int n_in,
                              void* d_out, int out_size, void* d_ws, size_t ws_size,
                              hipStream_t stream) {
    const float* x       = (const float*)d_in[0];
    const int*   ei      = (const int*)d_in[1];
    const float* W       = (const float*)d_in[2];
    const float* att_src = (const float*)d_in[3];
    const float* att_dst = (const float*)d_in[4];
    const float* bias    = (const float*)d_in[5];

    const int N = in_sizes[0] / IN_DIM;   // 50000
    const int E = in_sizes[1] / 2;        // 800000
    const int ET = E + N;
    const int NT = (N + 255) / 256;       // 196 scan tiles

    // ws: wa_s | wa_d | Wfrag | a_src | a_dst | indptr | cnt | bsum | slots | xb | wslots
    char* ws = (char*)d_ws;
    size_t off = 0;
    float* wa_s   = (float*)(ws + off); off += HEADS * IN_DIM * 4;
    float* wa_d   = (float*)(ws + off); off += HEADS * IN_DIM * 4;
    u16*   Wfrag  = (u16*)(ws + off);   off += 32768 * 2;
    float* a_src  = (float*)(ws + off); off += (size_t)N * HEADS * 4;
    float* a_dst  = (float*)(ws + off); off += (size_t)N * HEADS * 4;
    int*   indptr = (int*)(ws + off);   off += ((size_t)(N + 1) * 4 + 15) & ~(size_t)15;
    int*   cnt    = (int*)(ws + off);   off += ((size_t)N * 4 + 15) & ~(size_t)15;
    int*   bsum   = (int*)(ws + off);   off += 1024 * 4;
    int*   slots  = (int*)(ws + off);   off += ((size_t)ET * 4 + 15) & ~(size_t)15;
    u16*   xb     = (u16*)(ws + off);   size_t need_bf = off + (size_t)N * IN_DIM * 2;
    uint2* wslots = (uint2*)(ws + need_bf);
    size_t need_w = need_bf + (size_t)ET * 8;
    bool use_bf = (ws_size >= need_bf);
    bool use_w  = (ws_size >= need_w);

    const int NA = (N + 3) / 4;           // logits+xcvt blocks (wave per node)
    const int NC = (ET + 255) / 256;      // count blocks

    init_kernel<<<NT + 1, 256, 0, stream>>>(W, att_src, att_dst, wa_s, wa_d, cnt, N, NT);
    phase1_kernel<<<NA + NC + 8, 256, 0, stream>>>(x, ei, W, wa_s, wa_d, a_src, a_dst,
                                                   use_bf ? xb : (u16*)d_out,
                                                   Wfrag, cnt, N, E, NA, NC);
    scan1_kernel<<<NT, 256, 0, stream>>>(cnt, indptr, bsum, N);
    scan2_kernel<<<1, 1024, 0, stream>>>(bsum, NT);
    scan3_kernel<<<NT, 256, 0, stream>>>(indptr, bsum, cnt, N);
    fill_kernel<<<(ET + 255) / 256, 256, 0, stream>>>(ei, indptr, cnt, slots,
                                                      use_w ? wslots : (uint2*)0,
                                                      a_src, a_dst, E, N);
    if (use_w) {
        int nwaves = (N + 3) / 4;
        gather_w_kernel<<<(nwaves * 64 + 511) / 512, 512, 0, stream>>>(indptr, slots,
                                                                       wslots, xb,
                                                                       (u16*)d_out, N, ET);
    } else if (use_bf) {
        gather_bf_kernel<<<(N * 64 + 511) / 512, 512, 0, stream>>>(indptr, slots, xb,
                                                                   a_src, a_dst,
                                                                   (u16*)d_out, N, ET);
    } else {
        gather_f32_kernel<<<(N * 64 + 511) / 512, 512, 0, stream>>>(indptr, slots, x,
                                                                    a_src, a_dst,
                                                                    (u16*)d_out, N, ET);
    }
    zgemm_kernel<<<(N + 15) / 16, 256, 0, stream>>>(Wfrag, bias, (float*)d_out, N);
}